// Round 7
// baseline (520.772 us; speedup 1.0000x reference)
//
#include <hip/hip_runtime.h>

#define L_    2048
#define DIM_  3072
#define H_    24
#define D_    128
#define NQKV  9216   // 3*DIM

typedef __attribute__((ext_vector_type(8))) short bf16x8;   // 8 bf16 = 4 VGPRs
typedef __attribute__((ext_vector_type(4))) short bf16x4;   // 4 bf16 = 2 VGPRs
typedef __attribute__((ext_vector_type(4))) float f32x4;
typedef __attribute__((ext_vector_type(16))) float f32x16;

__device__ __forceinline__ unsigned short f2bf(float f) {
  union { float f; unsigned u; } v; v.f = f;
  unsigned r = v.u + 0x7fffu + ((v.u >> 16) & 1u);   // RNE
  return (unsigned short)(r >> 16);
}

// async global->LDS, 16B per lane. LDS dest = wave-uniform base + lane*16.
__device__ __forceinline__ void gload_lds16(const void* g, void* l) {
  auto* lp = reinterpret_cast<__attribute__((address_space(3))) unsigned int*>(
      reinterpret_cast<uintptr_t>(l));
  auto* gp = reinterpret_cast<const __attribute__((address_space(1))) unsigned int*>(
      reinterpret_cast<uintptr_t>(g));
  __builtin_amdgcn_global_load_lds(gp, lp, 16, 0, 0);
}

// ---------------------------------------------------------------- all casts, ONE launch
// by < 144:   w_qkv  [3072][9216] f32 -> w_qkvT  [9216][3072] bf16 (reg-transposed)
// by < 192:   w_proj [3072][3072] f32 -> w_projT [3072][3072] bf16 (reg-transposed)
// else:       x      [2048][3072] f32 -> x_b (straight cast, grid-stride)
__global__ __launch_bounds__(256)
void castAll(const float* __restrict__ x,  unsigned short* __restrict__ xb,
             const float* __restrict__ w0, unsigned short* __restrict__ o0,
             const float* __restrict__ w1, unsigned short* __restrict__ o1) {
  const int K = 3072;
  const int by = blockIdx.y;
  if (by >= 192) {
    int blk = (by - 192) * 24 + blockIdx.x;
    int total = (L_ * DIM_) >> 2;
    int stride = 2304 * 256;
    for (int i = blk * 256 + threadIdx.x; i < total; i += stride) {
      float4 v = ((const float4*)x)[i];
      ushort4 o;
      o.x = f2bf(v.x); o.y = f2bf(v.y); o.z = f2bf(v.z); o.w = f2bf(v.w);
      ((ushort4*)xb)[i] = o;
    }
    return;
  }
  const float* in; unsigned short* out; int N, n0;
  if (by < 144) { in = w0; out = o0; N = 9216; n0 = by * 64; }
  else          { in = w1; out = o1; N = 3072; n0 = (by - 144) * 64; }
  const int tid  = threadIdx.x;
  const int lane = tid & 63;
  const int wave = tid >> 6;
  const int nq = lane & 7;
  const int kq = lane >> 3;
  const int k0 = blockIdx.x * 128 + (wave & 1) * 64 + kq * 8;
  const int nb = n0 + (wave >> 1) * 32 + nq * 4;
  float4 v[8];
  #pragma unroll
  for (int i = 0; i < 8; i++)
    v[i] = *(const float4*)&in[(size_t)(k0 + i) * N + nb];
  #pragma unroll
  for (int j = 0; j < 4; j++) {
    bf16x8 o;
    #pragma unroll
    for (int i = 0; i < 8; i++)
      o[i] = (short)f2bf(((const float*)&v[i])[j]);
    *(bf16x8*)&out[(size_t)(nb + j) * K + k0] = o;
  }
}

// ---------------------------------------------------------------- QKV GEMM + RMS/RoPE
// qkv[M][9216] = x[M][3072] * w_qkvT[9216][3072]^T.  128x128 tile; 8x8 supertile
// XCD swizzle. V-heads: fused LDS transpose epilogue writes Vt[h][d][l].
// Q scaled by 1/sqrt(128)*log2(e) so flash_attn softmax runs in exp2 domain.
__global__ __launch_bounds__(256, 3)
void gemm_qkv(const unsigned short* __restrict__ A,
              const unsigned short* __restrict__ Bt,
              const float* __restrict__ pe,        // [L][64][2][2]
              const float* __restrict__ q_scale,
              const float* __restrict__ k_scale,
              unsigned short* __restrict__ Qo,     // [H][L][D]
              unsigned short* __restrict__ Ko,     // [H][L][D]
              unsigned short* __restrict__ Vt)     // [H][D][L]
{
  const int K = DIM_;
  __shared__ __align__(16) unsigned short S[128 * 132];   // 33792 B
  unsigned short* As = S;
  unsigned short* Bs = S + 128 * 64;
  const int tid  = threadIdx.x;
  const int wave = tid >> 6;
  const int lane = tid & 63;
  const int l15  = lane & 15;
  const int quad = lane >> 4;
  const int wm = wave >> 1, wn = wave & 1;

  const int lin = blockIdx.x;
  const int st  = lin >> 6;
  const int w6  = lin & 63;
  const int bn_idx = (st >> 1) * 8 + (w6 & 7);    // 0..71
  const int bm_idx = (st & 1) * 8 + (w6 >> 3);    // 0..15
  const int bm = bm_idx * 128;
  const int bn = bn_idx * 128;

  const int srow = lane >> 3;
  const int scol = (lane & 7) ^ srow;
  const unsigned short* Ag = A  + (size_t)(bm + wave * 32 + srow) * K + scol * 8;
  const unsigned short* Bg = Bt + (size_t)(bn + wave * 32 + srow) * K + scol * 8;
  unsigned short* Al = &As[(wave * 32) * 64];
  unsigned short* Bl = &Bs[(wave * 32) * 64];

  f32x4 acc[4][4];
  #pragma unroll
  for (int i = 0; i < 4; i++)
    #pragma unroll
    for (int j = 0; j < 4; j++) acc[i][j] = (f32x4){0.f, 0.f, 0.f, 0.f};

  for (int k0 = 0; k0 < K; k0 += 64) {
    __syncthreads();
    #pragma unroll
    for (int j = 0; j < 4; j++) {
      gload_lds16(Ag + (size_t)j * 8 * K + k0, Al + j * 8 * 64);
      gload_lds16(Bg + (size_t)j * 8 * K + k0, Bl + j * 8 * 64);
    }
    __syncthreads();
    #pragma unroll
    for (int ks = 0; ks < 2; ks++) {
      const int cph = ((ks * 4 + quad) ^ (l15 & 7)) * 8;
      bf16x8 af[4], bf[4];
      #pragma unroll
      for (int mt = 0; mt < 4; mt++)
        af[mt] = *(const bf16x8*)&As[(wm * 64 + mt * 16 + l15) * 64 + cph];
      #pragma unroll
      for (int nt = 0; nt < 4; nt++)
        bf[nt] = *(const bf16x8*)&Bs[(wn * 64 + nt * 16 + l15) * 64 + cph];
      #pragma unroll
      for (int mt = 0; mt < 4; mt++)
        #pragma unroll
        for (int nt = 0; nt < 4; nt++)
          acc[mt][nt] = __builtin_amdgcn_mfma_f32_16x16x32_bf16(
              af[mt], bf[nt], acc[mt][nt], 0, 0, 0);
    }
  }
  __syncthreads();

  if (bn_idx < 48) {
    const bool isQ = bn_idx < 24;
    const int  hh  = isQ ? bn_idx : bn_idx - 24;
    const float* sc = isQ ? q_scale : k_scale;
    unsigned short* dst = isQ ? Qo : Ko;
    float* rbuf = (float*)S;
    #pragma unroll
    for (int mt = 0; mt < 4; mt++)
      #pragma unroll
      for (int r = 0; r < 4; r++) {
        float p = 0.f;
        #pragma unroll
        for (int nt = 0; nt < 4; nt++) p += acc[mt][nt][r] * acc[mt][nt][r];
        p += __shfl_xor(p, 1); p += __shfl_xor(p, 2);
        p += __shfl_xor(p, 4); p += __shfl_xor(p, 8);
        if (l15 == 0) rbuf[wn * 128 + wm * 64 + mt * 16 + quad * 4 + r] = p;
      }
    __syncthreads();
    #pragma unroll
    for (int mt = 0; mt < 4; mt++)
      #pragma unroll
      for (int r = 0; r < 4; r++) {
        const int lrow = wm * 64 + mt * 16 + quad * 4 + r;
        const int lg = bm + lrow;
        float ms = (rbuf[lrow] + rbuf[128 + lrow]) * (1.f / 128.f);
        float rinv = rsqrtf(ms + 1e-6f);
        #pragma unroll
        for (int nt = 0; nt < 4; nt++) {
          const int d = wn * 64 + nt * 16 + l15;
          float n  = acc[mt][nt][r] * rinv * sc[d];
          float np = __shfl_xor(n, 1);
          float2 ab = *(const float2*)&pe[(size_t)lg * 256 + (d >> 1) * 4 + (d & 1) * 2];
          float xe = (d & 1) ? np : n;
          float xo = (d & 1) ? n  : np;
          float o = ab.x * xe + ab.y * xo;
          if (isQ) o *= (0.08838834764831845f * 1.4426950408889634f);
          dst[((size_t)hh * L_ + lg) * D_ + d] = f2bf(o);
        }
      }
  } else {
    const int hh = bn_idx - 48;
    unsigned short (*St)[132] = (unsigned short(*)[132])S;
    #pragma unroll
    for (int mt = 0; mt < 4; mt++)
      #pragma unroll
      for (int nt = 0; nt < 4; nt++)
        #pragma unroll
        for (int r = 0; r < 4; r++) {
          int row = wm * 64 + mt * 16 + quad * 4 + r;
          int col = wn * 64 + nt * 16 + l15;
          St[row][col] = f2bf(acc[mt][nt][r]);
        }
    __syncthreads();
    const int grp = tid >> 6;
    const int ll  = tid & 63;
    unsigned short* dstV = Vt + (size_t)hh * D_ * L_;
    #pragma unroll
    for (int dd = 0; dd < 32; dd += 4) {
      const int d = grp * 32 + dd;
      #pragma unroll
      for (int half = 0; half < 2; half++) {
        const int l = ll + half * 64;
        bf16x4 v4 = *(const bf16x4*)&St[l][d];
        #pragma unroll
        for (int j = 0; j < 4; j++)
          dstV[(size_t)(d + j) * L_ + bm + l] = ((const unsigned short*)&v4)[j];
      }
    }
  }
}

// ---------------------------------------------------------------- proj GEMM (no split-K)
// out[M][N] f32 = A[M][3072] * Bt[N][3072]^T + bias[N].  Grid 384, co-resident,
// 8x8 supertile XCD swizzle, bias fused in epilogue.
__global__ __launch_bounds__(256, 3)
void gemm_proj(const unsigned short* __restrict__ A,
               const unsigned short* __restrict__ Bt,
               const float* __restrict__ bias,
               float* __restrict__ out,
               int M, int N, int K)
{
  __shared__ unsigned short As[128 * 64];
  __shared__ unsigned short Bs[128 * 64];
  const int tid  = threadIdx.x;
  const int wave = tid >> 6;
  const int lane = tid & 63;
  const int l15  = lane & 15;
  const int quad = lane >> 4;
  const int wm = wave >> 1, wn = wave & 1;
  const int lin = blockIdx.x;
  const int st  = lin >> 6;
  const int w6  = lin & 63;
  const int bn = ((st >> 1) * 8 + (w6 & 7)) * 128;
  const int bm = ((st & 1) * 8 + (w6 >> 3)) * 128;

  const int srow = lane >> 3;
  const int scol = (lane & 7) ^ srow;
  const unsigned short* Ag = A  + (size_t)(bm + wave * 32 + srow) * K + scol * 8;
  const unsigned short* Bg = Bt + (size_t)(bn + wave * 32 + srow) * K + scol * 8;
  unsigned short* Al = &As[(wave * 32) * 64];
  unsigned short* Bl = &Bs[(wave * 32) * 64];

  f32x4 acc[4][4];
  #pragma unroll
  for (int i = 0; i < 4; i++)
    #pragma unroll
    for (int j = 0; j < 4; j++) acc[i][j] = (f32x4){0.f, 0.f, 0.f, 0.f};

  for (int k0 = 0; k0 < K; k0 += 64) {
    __syncthreads();
    #pragma unroll
    for (int j = 0; j < 4; j++) {
      gload_lds16(Ag + (size_t)j * 8 * K + k0, Al + j * 8 * 64);
      gload_lds16(Bg + (size_t)j * 8 * K + k0, Bl + j * 8 * 64);
    }
    __syncthreads();
    #pragma unroll
    for (int ks = 0; ks < 2; ks++) {
      const int cph = ((ks * 4 + quad) ^ (l15 & 7)) * 8;
      bf16x8 af[4], bf[4];
      #pragma unroll
      for (int mt = 0; mt < 4; mt++)
        af[mt] = *(const bf16x8*)&As[(wm * 64 + mt * 16 + l15) * 64 + cph];
      #pragma unroll
      for (int nt = 0; nt < 4; nt++)
        bf[nt] = *(const bf16x8*)&Bs[(wn * 64 + nt * 16 + l15) * 64 + cph];
      #pragma unroll
      for (int mt = 0; mt < 4; mt++)
        #pragma unroll
        for (int nt = 0; nt < 4; nt++)
          acc[mt][nt] = __builtin_amdgcn_mfma_f32_16x16x32_bf16(
              af[mt], bf[nt], acc[mt][nt], 0, 0, 0);
    }
  }
  float bcol[4];
  #pragma unroll
  for (int nt = 0; nt < 4; nt++)
    bcol[nt] = bias[bn + wn * 64 + nt * 16 + l15];
  #pragma unroll
  for (int mt = 0; mt < 4; mt++)
    #pragma unroll
    for (int nt = 0; nt < 4; nt++)
      #pragma unroll
      for (int r = 0; r < 4; r++) {
        int row = bm + wm * 64 + mt * 16 + quad * 4 + r;
        int col = bn + wn * 64 + nt * 16 + l15;
        out[(size_t)row * N + col] = acc[mt][nt][r] + bcol[nt];
      }
}

// ---------------------------------------------------------------- flash attention v2
// 32x32-MFMA swapped-QK structure (m214-class). Block: 2 waves x 32 queries,
// KVBLK = 32 keys/tile, one head. S^T = K*Q^T via mfma_32x32x16: lane's query
// = lane&31 for BOTH S and O => softmax max/sum need one shfl_xor(32); rescale
// and 1/l are pure lane-local; NO cross-wave merge epilogue.
//   QK: A = K[key][d] (LDS, 8 frags), B = Q (regs).  8 MFMA / tile / wave.
//   PV: O^T[d][q]: A = V^T[d][key] (LDS), B = P^T (regs). 8 MFMA / tile / wave.
// P redistribution (S^T regs -> PV B-frags): key(r) = (r&3)+4*h5+8*(r>>2);
// B-frag kslot s needs keys s*16+h5*8+0..7 = half0-regs[8s+4h5..+3] (elems 0-3)
// + half1-regs[same] (elems 4-7) => each lane KEEPS words w[4s+2*h5],w[+1] and
// SENDS w[4s+2*(1-h5)],w[+1] via shfl_xor(32) (send/keep asymmetry!).
// LDS 24KB: K dbuf 2x8KB (swizzle chunk^=row&15, as verified) + V single 8KB
// [128d][32k] (swizzle chunk^=d&3). 6 blocks/CU, 12 waves/CU.
// Counted vmcnt(4), 3 barriers/tile (verified r3 schedule, 4-load granularity).
__global__ __launch_bounds__(128, 3)
void flash_attn(const unsigned short* __restrict__ Q,   // [H][L][D]
                const unsigned short* __restrict__ K,   // [H][L][D]
                const unsigned short* __restrict__ Vt,  // [H][D][L]
                unsigned short* __restrict__ Out)       // [L][DIM]
{
  __shared__ __align__(16) char smem[24576];
  // Ks buf b: smem + b*8192, [32][128] bf16, chunk(16B) ^= row&15
  // Vs:       smem + 16384,  [128][32] bf16, chunk(16B) ^= d&3

  const int tid  = threadIdx.x;
  const int wave = tid >> 6;          // 0,1
  const int lane = tid & 63;
  const int l31  = lane & 31;
  const int h5   = lane >> 5;         // MFMA operand half
  // XCD-clustered decode: 8 XCDs x 3 heads x 32 q-blocks (64 q each)
  const int id   = blockIdx.x;
  const int slot = id >> 3;
  const int h    = (id & 7) * 3 + slot % 3;
  const int q0w  = (slot / 3) * 64 + wave * 32;   // this wave's 32 queries

  const unsigned short* Qh = Q  + (size_t)h * L_ * D_;
  const unsigned short* Kh = K  + (size_t)h * L_ * D_;
  const unsigned short* Vh = Vt + (size_t)h * D_ * L_;

  // Q as B-operand of 32x32x16: col = q = l31, k = h5*8 + e  (8 k-chunks)
  bf16x8 qf[8];
  #pragma unroll
  for (int kc = 0; kc < 8; kc++)
    qf[kc] = *(const bf16x8*)&Qh[(size_t)(q0w + l31) * D_ + kc * 16 + h5 * 8];

  f32x16 oacc[4];     // O^T: dblock db, reg r -> d = db*32+(r&3)+8*(r>>2)+4*h5, q = l31
  #pragma unroll
  for (int i = 0; i < 4; i++)
    #pragma unroll
    for (int r = 0; r < 16; r++) oacc[i][r] = 0.f;
  float m_i = -1e30f, l_i = 0.f;

  // K staging: 4 calls/wave, 4 rows each (row = R0+lane>>4, phys chunk l15,
  // global chunk = l15 ^ (row&15))
  auto stageK = [&](int t, int b) {
    unsigned short* Kb = (unsigned short*)(smem + b * 8192);
    #pragma unroll
    for (int j = 0; j < 4; j++) {
      int R0 = wave * 16 + j * 4;
      int R  = R0 + (lane >> 4);
      gload_lds16(&Kh[(size_t)(t + R) * D_ + (((lane & 15) ^ (R & 15)) * 8)],
                  &Kb[R0 * 128]);
    }
  };
  // V staging: 4 calls/wave, 16 rows each (row d = R0+lane>>2, phys chunk
  // lane&3, global col chunk = (lane&3) ^ (d&3))
  auto stageV = [&](int t) {
    unsigned short* Vb = (unsigned short*)(smem + 16384);
    #pragma unroll
    for (int j = 0; j < 4; j++) {
      int R0 = wave * 64 + j * 16;
      int R  = R0 + (lane >> 2);
      gload_lds16(&Vh[(size_t)R * L_ + t + (((lane & 3) ^ (R & 3)) * 8)],
                  &Vb[R0 * 32]);
    }
  };

  stageK(0, 0);    // oldest 4
  stageV(0);       // next 4

  for (int t = 0; t < L_; t += 32) {
    const int cur  = (t >> 5) & 1;
    const bool more = (t + 32 < L_);

    // B1: K(t) resident; V(t) still in flight.
    asm volatile("s_waitcnt vmcnt(4)" ::: "memory");
    __builtin_amdgcn_s_barrier();
    if (more) stageK(t + 32, cur ^ 1);

    const unsigned short* Ksc = (const unsigned short*)(smem + cur * 8192);
    const unsigned short* Vsc = (const unsigned short*)(smem + 16384);

    // ---- QK^T: S^T[key][q], A = K (row=key=l31, k = kc*16+h5*8+e)
    f32x16 s;
    #pragma unroll
    for (int r = 0; r < 16; r++) s[r] = 0.f;
    __builtin_amdgcn_s_setprio(1);
    #pragma unroll
    for (int kc = 0; kc < 8; kc++) {
      bf16x8 kf = *(const bf16x8*)
          &Ksc[l31 * 128 + (((kc * 2 + h5) ^ (lane & 15)) * 8)];
      s = __builtin_amdgcn_mfma_f32_32x32x16_bf16(kf, qf[kc], s, 0, 0, 0);
    }
    __builtin_amdgcn_s_setprio(0);

    // ---- online softmax: lane holds 16 scores of query l31
    float a0 = fmaxf(fmaxf(s[0], s[1]), s[2]);
    a0 = fmaxf(fmaxf(a0, s[3]), s[4]);
    a0 = fmaxf(fmaxf(a0, s[5]), s[6]);
    a0 = fmaxf(fmaxf(a0, s[7]), s[8]);
    a0 = fmaxf(fmaxf(a0, s[9]), s[10]);
    a0 = fmaxf(fmaxf(a0, s[11]), s[12]);
    a0 = fmaxf(fmaxf(a0, s[13]), s[14]);
    a0 = fmaxf(a0, s[15]);
    float vmax = fmaxf(a0, __shfl_xor(a0, 32));
    // T13 defer-max, exp2 domain: skip rescale while growth <= 8*log2(e)
    if (!__all(vmax - m_i <= 11.5415603f)) {
      float mnew = fmaxf(m_i, vmax);
      float alpha = exp2f(m_i - mnew);
      m_i = mnew;
      l_i *= alpha;
      #pragma unroll
      for (int db = 0; db < 4; db++)
        #pragma unroll
        for (int r = 0; r < 16; r++) oacc[db][r] *= alpha;   // lane-local!
    }
    float rs = 0.f;
    #pragma unroll
    for (int r = 0; r < 16; r++) {
      float p = exp2f(s[r] - m_i);
      s[r] = p;
      rs += p;
    }
    rs += __shfl_xor(rs, 32);
    l_i += rs;

    // ---- pack P to bf16 words: w[j] = (bf16(s[2j]), bf16(s[2j+1]))
    unsigned int w[8];
    #pragma unroll
    for (int j = 0; j < 8; j++)
      asm("v_cvt_pk_bf16_f32 %0, %1, %2"
          : "=v"(w[j]) : "v"(s[2 * j]), "v"(s[2 * j + 1]));

    // ---- PV B-frags (P^T: col=q=l31, k=key s*16+h5*8+e), send/keep per half
    bf16x8 pb[2];
    #pragma unroll
    for (int ks = 0; ks < 2; ks++) {
      unsigned int keep0 = h5 ? w[4 * ks + 2] : w[4 * ks];
      unsigned int keep1 = h5 ? w[4 * ks + 3] : w[4 * ks + 1];
      unsigned int send0 = h5 ? w[4 * ks]     : w[4 * ks + 2];
      unsigned int send1 = h5 ? w[4 * ks + 1] : w[4 * ks + 3];
      unsigned int recv0 = __shfl_xor((int)send0, 32);
      unsigned int recv1 = __shfl_xor((int)send1, 32);
      union { unsigned int u[4]; bf16x8 v; } fb;
      fb.u[0] = h5 ? recv0 : keep0;
      fb.u[1] = h5 ? recv1 : keep1;
      fb.u[2] = h5 ? keep0 : recv0;
      fb.u[3] = h5 ? keep1 : recv1;
      pb[ks] = fb.v;
    }

    // B2: V(t) resident; K(t+32) prefetch stays in flight.
    if (more) asm volatile("s_waitcnt vmcnt(4)" ::: "memory");
    else      asm volatile("s_waitcnt vmcnt(0)" ::: "memory");
    __builtin_amdgcn_s_barrier();

    // ---- PV: O^T += V^T * P^T.  A = V^T (row=d=db*32+l31, k=key ks*16+h5*8+e)
    __builtin_amdgcn_s_setprio(1);
    #pragma unroll
    for (int db = 0; db < 4; db++) {
      #pragma unroll
      for (int ks = 0; ks < 2; ks++) {
        bf16x8 vf = *(const bf16x8*)
            &Vsc[(db * 32 + l31) * 32 + (((ks * 2 + h5) ^ (lane & 3)) * 8)];
        oacc[db] = __builtin_amdgcn_mfma_f32_32x32x16_bf16(vf, pb[ks], oacc[db], 0, 0, 0);
      }
    }
    __builtin_amdgcn_s_setprio(0);

    if (more) {
      __builtin_amdgcn_s_barrier();   // B3: all PV reads of Vs done
      stageV(t + 32);                 // drains at next B2
    }
  }

  // ---- epilogue: pure lane-local normalize + write own query's row
  float rinv = 1.f / l_i;
  const size_t obase = (size_t)(q0w + l31) * DIM_ + h * D_;
  #pragma unroll
  for (int db = 0; db < 4; db++)
    #pragma unroll
    for (int j = 0; j < 4; j++) {
      ushort4 o;
      o.x = f2bf(oacc[db][4 * j + 0] * rinv);
      o.y = f2bf(oacc[db][4 * j + 1] * rinv);
      o.z = f2bf(oacc[db][4 * j + 2] * rinv);
      o.w = f2bf(oacc[db][4 * j + 3] * rinv);
      *(ushort4*)&Out[obase + db * 32 + 8 * j + 4 * h5] = o;
    }
}

// ---------------------------------------------------------------- launcher
extern "C" void kernel_launch(void* const* d_in, const int* in_sizes, int n_in,
                              void* d_out, int out_size, void* d_ws, size_t ws_size,
                              hipStream_t stream) {
  const float* x       = (const float*)d_in[0];
  const float* pe      = (const float*)d_in[1];
  const float* w_qkv   = (const float*)d_in[2];
  const float* q_scale = (const float*)d_in[3];
  const float* k_scale = (const float*)d_in[4];
  const float* w_proj  = (const float*)d_in[5];
  const float* b_proj  = (const float*)d_in[6];

  unsigned short* w_qkvT  = (unsigned short*)d_ws;           // [9216][3072]
  unsigned short* w_projT = w_qkvT + 28311552;               // [3072][3072]
  unsigned short* x_b     = w_projT + 9437184;               // [2048][3072]
  unsigned short* q_r     = x_b + 6291456;                   // [H][L][D]
  unsigned short* k_r     = q_r + 6291456;
  unsigned short* vt_r    = k_r + 6291456;                   // [H][D][L]
  unsigned short* attn_b  = vt_r + 6291456;                  // [L][DIM]

  castAll<<<dim3(24, 288), 256, 0, stream>>>(
      x, x_b, w_qkv, w_qkvT, w_proj, w_projT);

  gemm_qkv<<<1152, 256, 0, stream>>>(
      x_b, w_qkvT, pe, q_scale, k_scale, q_r, k_r, vt_r);

  flash_attn<<<768, 128, 0, stream>>>(q_r, k_r, vt_r, attn_b);

  gemm_proj<<<384, 256, 0, stream>>>(
      attn_b, w_projT, b_proj, (float*)d_out, 2048, 3072, 3072);
}

// Round 8
// 502.257 us; speedup vs baseline: 1.0369x; 1.0369x over previous
//
#include <hip/hip_runtime.h>

#define L_    2048
#define DIM_  3072
#define H_    24
#define D_    128
#define NQKV  9216   // 3*DIM

typedef __attribute__((ext_vector_type(8))) short bf16x8;   // 8 bf16 = 4 VGPRs
typedef __attribute__((ext_vector_type(4))) short bf16x4;   // 4 bf16 = 2 VGPRs
typedef __attribute__((ext_vector_type(4))) float f32x4;

__device__ __forceinline__ unsigned short f2bf(float f) {
  union { float f; unsigned u; } v; v.f = f;
  unsigned r = v.u + 0x7fffu + ((v.u >> 16) & 1u);   // RNE
  return (unsigned short)(r >> 16);
}

// async global->LDS, 16B per lane. LDS dest = wave-uniform base + lane*16.
__device__ __forceinline__ void gload_lds16(const void* g, void* l) {
  auto* lp = reinterpret_cast<__attribute__((address_space(3))) unsigned int*>(
      reinterpret_cast<uintptr_t>(l));
  auto* gp = reinterpret_cast<const __attribute__((address_space(1))) unsigned int*>(
      reinterpret_cast<uintptr_t>(g));
  __builtin_amdgcn_global_load_lds(gp, lp, 16, 0, 0);
}

// ---------------------------------------------------------------- all casts, ONE launch
// by < 144:   w_qkv  [3072][9216] f32 -> w_qkvT  [9216][3072] bf16 (reg-transposed)
// by < 192:   w_proj [3072][3072] f32 -> w_projT [3072][3072] bf16 (reg-transposed)
// else:       x      [2048][3072] f32 -> x_b (straight cast, grid-stride)
__global__ __launch_bounds__(256)
void castAll(const float* __restrict__ x,  unsigned short* __restrict__ xb,
             const float* __restrict__ w0, unsigned short* __restrict__ o0,
             const float* __restrict__ w1, unsigned short* __restrict__ o1) {
  const int K = 3072;
  const int by = blockIdx.y;
  if (by >= 192) {
    int blk = (by - 192) * 24 + blockIdx.x;
    int total = (L_ * DIM_) >> 2;
    int stride = 2304 * 256;
    for (int i = blk * 256 + threadIdx.x; i < total; i += stride) {
      float4 v = ((const float4*)x)[i];
      ushort4 o;
      o.x = f2bf(v.x); o.y = f2bf(v.y); o.z = f2bf(v.z); o.w = f2bf(v.w);
      ((ushort4*)xb)[i] = o;
    }
    return;
  }
  const float* in; unsigned short* out; int N, n0;
  if (by < 144) { in = w0; out = o0; N = 9216; n0 = by * 64; }
  else          { in = w1; out = o1; N = 3072; n0 = (by - 144) * 64; }
  const int tid  = threadIdx.x;
  const int lane = tid & 63;
  const int wave = tid >> 6;
  const int nq = lane & 7;
  const int kq = lane >> 3;
  const int k0 = blockIdx.x * 128 + (wave & 1) * 64 + kq * 8;
  const int nb = n0 + (wave >> 1) * 32 + nq * 4;
  float4 v[8];
  #pragma unroll
  for (int i = 0; i < 8; i++)
    v[i] = *(const float4*)&in[(size_t)(k0 + i) * N + nb];
  #pragma unroll
  for (int j = 0; j < 4; j++) {
    bf16x8 o;
    #pragma unroll
    for (int i = 0; i < 8; i++)
      o[i] = (short)f2bf(((const float*)&v[i])[j]);
    *(bf16x8*)&out[(size_t)(nb + j) * K + k0] = o;
  }
}

// ---------------------------------------------------------------- QKV GEMM + RMS/RoPE
// qkv[M][9216] = x[M][3072] * w_qkvT[9216][3072]^T.  128x128 tile; 8x8 supertile
// XCD swizzle. V-heads: fused LDS transpose epilogue writes Vt[h][d][l].
// Q scaled by 1/sqrt(128)*log2(e) so flash_attn softmax runs in exp2 domain.
__global__ __launch_bounds__(256, 3)
void gemm_qkv(const unsigned short* __restrict__ A,
              const unsigned short* __restrict__ Bt,
              const float* __restrict__ pe,        // [L][64][2][2]
              const float* __restrict__ q_scale,
              const float* __restrict__ k_scale,
              unsigned short* __restrict__ Qo,     // [H][L][D]
              unsigned short* __restrict__ Ko,     // [H][L][D]
              unsigned short* __restrict__ Vt)     // [H][D][L]
{
  const int K = DIM_;
  __shared__ __align__(16) unsigned short S[128 * 132];   // 33792 B
  unsigned short* As = S;
  unsigned short* Bs = S + 128 * 64;
  const int tid  = threadIdx.x;
  const int wave = tid >> 6;
  const int lane = tid & 63;
  const int l15  = lane & 15;
  const int quad = lane >> 4;
  const int wm = wave >> 1, wn = wave & 1;

  const int lin = blockIdx.x;
  const int st  = lin >> 6;
  const int w6  = lin & 63;
  const int bn_idx = (st >> 1) * 8 + (w6 & 7);    // 0..71
  const int bm_idx = (st & 1) * 8 + (w6 >> 3);    // 0..15
  const int bm = bm_idx * 128;
  const int bn = bn_idx * 128;

  const int srow = lane >> 3;
  const int scol = (lane & 7) ^ srow;
  const unsigned short* Ag = A  + (size_t)(bm + wave * 32 + srow) * K + scol * 8;
  const unsigned short* Bg = Bt + (size_t)(bn + wave * 32 + srow) * K + scol * 8;
  unsigned short* Al = &As[(wave * 32) * 64];
  unsigned short* Bl = &Bs[(wave * 32) * 64];

  f32x4 acc[4][4];
  #pragma unroll
  for (int i = 0; i < 4; i++)
    #pragma unroll
    for (int j = 0; j < 4; j++) acc[i][j] = (f32x4){0.f, 0.f, 0.f, 0.f};

  for (int k0 = 0; k0 < K; k0 += 64) {
    __syncthreads();
    #pragma unroll
    for (int j = 0; j < 4; j++) {
      gload_lds16(Ag + (size_t)j * 8 * K + k0, Al + j * 8 * 64);
      gload_lds16(Bg + (size_t)j * 8 * K + k0, Bl + j * 8 * 64);
    }
    __syncthreads();
    #pragma unroll
    for (int ks = 0; ks < 2; ks++) {
      const int cph = ((ks * 4 + quad) ^ (l15 & 7)) * 8;
      bf16x8 af[4], bf[4];
      #pragma unroll
      for (int mt = 0; mt < 4; mt++)
        af[mt] = *(const bf16x8*)&As[(wm * 64 + mt * 16 + l15) * 64 + cph];
      #pragma unroll
      for (int nt = 0; nt < 4; nt++)
        bf[nt] = *(const bf16x8*)&Bs[(wn * 64 + nt * 16 + l15) * 64 + cph];
      #pragma unroll
      for (int mt = 0; mt < 4; mt++)
        #pragma unroll
        for (int nt = 0; nt < 4; nt++)
          acc[mt][nt] = __builtin_amdgcn_mfma_f32_16x16x32_bf16(
              af[mt], bf[nt], acc[mt][nt], 0, 0, 0);
    }
  }
  __syncthreads();

  if (bn_idx < 48) {
    const bool isQ = bn_idx < 24;
    const int  hh  = isQ ? bn_idx : bn_idx - 24;
    const float* sc = isQ ? q_scale : k_scale;
    unsigned short* dst = isQ ? Qo : Ko;
    float* rbuf = (float*)S;
    #pragma unroll
    for (int mt = 0; mt < 4; mt++)
      #pragma unroll
      for (int r = 0; r < 4; r++) {
        float p = 0.f;
        #pragma unroll
        for (int nt = 0; nt < 4; nt++) p += acc[mt][nt][r] * acc[mt][nt][r];
        p += __shfl_xor(p, 1); p += __shfl_xor(p, 2);
        p += __shfl_xor(p, 4); p += __shfl_xor(p, 8);
        if (l15 == 0) rbuf[wn * 128 + wm * 64 + mt * 16 + quad * 4 + r] = p;
      }
    __syncthreads();
    #pragma unroll
    for (int mt = 0; mt < 4; mt++)
      #pragma unroll
      for (int r = 0; r < 4; r++) {
        const int lrow = wm * 64 + mt * 16 + quad * 4 + r;
        const int lg = bm + lrow;
        float ms = (rbuf[lrow] + rbuf[128 + lrow]) * (1.f / 128.f);
        float rinv = rsqrtf(ms + 1e-6f);
        #pragma unroll
        for (int nt = 0; nt < 4; nt++) {
          const int d = wn * 64 + nt * 16 + l15;
          float n  = acc[mt][nt][r] * rinv * sc[d];
          float np = __shfl_xor(n, 1);
          float2 ab = *(const float2*)&pe[(size_t)lg * 256 + (d >> 1) * 4 + (d & 1) * 2];
          float xe = (d & 1) ? np : n;
          float xo = (d & 1) ? n  : np;
          float o = ab.x * xe + ab.y * xo;
          if (isQ) o *= (0.08838834764831845f * 1.4426950408889634f);
          dst[((size_t)hh * L_ + lg) * D_ + d] = f2bf(o);
        }
      }
  } else {
    const int hh = bn_idx - 48;
    unsigned short (*St)[132] = (unsigned short(*)[132])S;
    #pragma unroll
    for (int mt = 0; mt < 4; mt++)
      #pragma unroll
      for (int nt = 0; nt < 4; nt++)
        #pragma unroll
        for (int r = 0; r < 4; r++) {
          int row = wm * 64 + mt * 16 + quad * 4 + r;
          int col = wn * 64 + nt * 16 + l15;
          St[row][col] = f2bf(acc[mt][nt][r]);
        }
    __syncthreads();
    const int grp = tid >> 6;
    const int ll  = tid & 63;
    unsigned short* dstV = Vt + (size_t)hh * D_ * L_;
    #pragma unroll
    for (int dd = 0; dd < 32; dd += 4) {
      const int d = grp * 32 + dd;
      #pragma unroll
      for (int half = 0; half < 2; half++) {
        const int l = ll + half * 64;
        bf16x4 v4 = *(const bf16x4*)&St[l][d];
        #pragma unroll
        for (int j = 0; j < 4; j++)
          dstV[(size_t)(d + j) * L_ + bm + l] = ((const unsigned short*)&v4)[j];
      }
    }
  }
}

// ---------------------------------------------------------------- proj GEMM (no split-K)
// out[M][N] f32 = A[M][3072] * Bt[N][3072]^T + bias[N].  Grid 384, co-resident,
// 8x8 supertile XCD swizzle, bias fused in epilogue.
__global__ __launch_bounds__(256, 3)
void gemm_proj(const unsigned short* __restrict__ A,
               const unsigned short* __restrict__ Bt,
               const float* __restrict__ bias,
               float* __restrict__ out,
               int M, int N, int K)
{
  __shared__ unsigned short As[128 * 64];
  __shared__ unsigned short Bs[128 * 64];
  const int tid  = threadIdx.x;
  const int wave = tid >> 6;
  const int lane = tid & 63;
  const int l15  = lane & 15;
  const int quad = lane >> 4;
  const int wm = wave >> 1, wn = wave & 1;
  const int lin = blockIdx.x;
  const int st  = lin >> 6;
  const int w6  = lin & 63;
  const int bn = ((st >> 1) * 8 + (w6 & 7)) * 128;
  const int bm = ((st & 1) * 8 + (w6 >> 3)) * 128;

  const int srow = lane >> 3;
  const int scol = (lane & 7) ^ srow;
  const unsigned short* Ag = A  + (size_t)(bm + wave * 32 + srow) * K + scol * 8;
  const unsigned short* Bg = Bt + (size_t)(bn + wave * 32 + srow) * K + scol * 8;
  unsigned short* Al = &As[(wave * 32) * 64];
  unsigned short* Bl = &Bs[(wave * 32) * 64];

  f32x4 acc[4][4];
  #pragma unroll
  for (int i = 0; i < 4; i++)
    #pragma unroll
    for (int j = 0; j < 4; j++) acc[i][j] = (f32x4){0.f, 0.f, 0.f, 0.f};

  for (int k0 = 0; k0 < K; k0 += 64) {
    __syncthreads();
    #pragma unroll
    for (int j = 0; j < 4; j++) {
      gload_lds16(Ag + (size_t)j * 8 * K + k0, Al + j * 8 * 64);
      gload_lds16(Bg + (size_t)j * 8 * K + k0, Bl + j * 8 * 64);
    }
    __syncthreads();
    #pragma unroll
    for (int ks = 0; ks < 2; ks++) {
      const int cph = ((ks * 4 + quad) ^ (l15 & 7)) * 8;
      bf16x8 af[4], bf[4];
      #pragma unroll
      for (int mt = 0; mt < 4; mt++)
        af[mt] = *(const bf16x8*)&As[(wm * 64 + mt * 16 + l15) * 64 + cph];
      #pragma unroll
      for (int nt = 0; nt < 4; nt++)
        bf[nt] = *(const bf16x8*)&Bs[(wn * 64 + nt * 16 + l15) * 64 + cph];
      #pragma unroll
      for (int mt = 0; mt < 4; mt++)
        #pragma unroll
        for (int nt = 0; nt < 4; nt++)
          acc[mt][nt] = __builtin_amdgcn_mfma_f32_16x16x32_bf16(
              af[mt], bf[nt], acc[mt][nt], 0, 0, 0);
    }
  }
  float bcol[4];
  #pragma unroll
  for (int nt = 0; nt < 4; nt++)
    bcol[nt] = bias[bn + wn * 64 + nt * 16 + l15];
  #pragma unroll
  for (int mt = 0; mt < 4; mt++)
    #pragma unroll
    for (int nt = 0; nt < 4; nt++)
      #pragma unroll
      for (int r = 0; r < 4; r++) {
        int row = bm + wm * 64 + mt * 16 + quad * 4 + r;
        int col = bn + wn * 64 + nt * 16 + l15;
        out[(size_t)row * N + col] = acc[mt][nt][r] + bcol[nt];
      }
}

// ---------------------------------------------------------------- flash attention
// Proven r6 version (best measured structure). Block: 4 waves, 64 queries,
// one head. Wave = (qg, kh): q-group of 32, key-half of the shared 64-key
// tile. S^T = K*Q^T so softmax is lane-indexed (q = l15) and P stays in
// registers as A-frags for mfma_16x16x16 PV. K double-buffered (2x16KB),
// V single (16KB) => 48KB LDS, 3 blocks/CU, 12 waves/CU.
// Counted vmcnt(4): K(t+64) prefetch stays in flight across both barriers;
// V(t+64) issues after post-PV barrier. T13 defer-max, T5 setprio.
// exp2-domain softmax (log2e folded into Q by gemm_qkv); P packed via
// v_cvt_pk_bf16_f32 (RNE = f2bf bits).
// Grid: 1D 768 with XCD clustering — id&7 = XCD, 3 heads per XCD (L2-fit).
__global__ __launch_bounds__(256, 3)
void flash_attn(const unsigned short* __restrict__ Q,   // [H][L][D]
                const unsigned short* __restrict__ K,   // [H][L][D]
                const unsigned short* __restrict__ Vt,  // [H][D][L]
                unsigned short* __restrict__ Out)       // [L][DIM]
{
  __shared__ __align__(16) char smem[49152];
  // Ks buf b: smem + b*16384, [64][128] swizzled(16)   (2 bufs, 32KB)
  // Vs:       smem + 32768,   [128][64] swizzled(8)    (16KB)
  float*  Obuf = (float*)smem;                         // merge: [64][128] f32 (aliases Ks, post-loop)
  float2* mlb  = (float2*)(smem + 32768);              // [64]   (aliases Vs, post-loop)
  float4* sAr  = (float4*)(smem + 33280);              // [64]

  const int tid  = threadIdx.x;
  const int wave = tid >> 6;
  const int lane = tid & 63;
  const int l15  = lane & 15;
  const int quad = lane >> 4;
  const int qg = wave >> 1;
  const int kh = wave & 1;
  // XCD-clustered decode: 8 XCDs x 3 heads x 32 q-blocks
  const int id   = blockIdx.x;
  const int slot = id >> 3;
  const int h    = (id & 7) * 3 + slot % 3;
  const int q0   = (slot / 3) * 64 + qg * 32;

  const unsigned short* Qh = Q  + (size_t)h * L_ * D_;
  const unsigned short* Kh = K  + (size_t)h * L_ * D_;
  const unsigned short* Vh = Vt + (size_t)h * D_ * L_;

  bf16x8 qf[2][4];
  #pragma unroll
  for (int nt = 0; nt < 2; nt++)
    #pragma unroll
    for (int kc = 0; kc < 4; kc++)
      qf[nt][kc] = *(const bf16x8*)&Qh[(size_t)(q0 + nt * 16 + l15) * D_ + kc * 32 + quad * 8];

  f32x4 oacc[2][8];
  #pragma unroll
  for (int i = 0; i < 2; i++)
    #pragma unroll
    for (int j = 0; j < 8; j++) oacc[i][j] = (f32x4){0.f, 0.f, 0.f, 0.f};
  float m_i[2] = {-1e30f, -1e30f}, l_i[2] = {0.f, 0.f};

  const int kr_l = lane >> 4;
  const int vr_l = lane >> 3;
  const int vcl  = (lane & 7) ^ vr_l;

  // 4 gload_lds per wave each; K before V so K is always the older group.
  auto stageK = [&](int t, int b) {
    unsigned short* Ksb = (unsigned short*)(smem + b * 16384);
    #pragma unroll
    for (int ji = 0; ji < 4; ji++) {
      int Rr = wave * 16 + ji * 4;
      int cl = l15 ^ ((Rr + kr_l) & 15);
      gload_lds16(&Kh[(size_t)(t + Rr + kr_l) * D_ + cl * 8], &Ksb[Rr * 128]);
    }
  };
  auto stageV = [&](int t) {
    unsigned short* Vsb = (unsigned short*)(smem + 32768);
    #pragma unroll
    for (int ji = 0; ji < 4; ji++) {
      int R2 = wave * 32 + ji * 8;
      gload_lds16(&Vh[(size_t)(R2 + vr_l) * L_ + t + vcl * 8], &Vsb[R2 * 64]);
    }
  };

  stageK(0, 0);    // oldest 4
  stageV(0);       // next 4

  for (int t = 0; t < L_; t += 64) {
    const int cur = (t >> 6) & 1;
    const bool more = (t + 64 < L_);

    // B1: K(t) resident for all waves; V(t) still in flight.
    asm volatile("s_waitcnt vmcnt(4)" ::: "memory");
    __builtin_amdgcn_s_barrier();
    if (more) stageK(t + 64, cur ^ 1);   // prefetch next K tile

    const unsigned short* Ksc = (const unsigned short*)(smem + cur * 16384);
    const unsigned short* Vsc = (const unsigned short*)(smem + 32768);

    f32x4 s[2][2];
    #pragma unroll
    for (int i = 0; i < 2; i++)
      #pragma unroll
      for (int j = 0; j < 2; j++) s[i][j] = (f32x4){0.f, 0.f, 0.f, 0.f};
    __builtin_amdgcn_s_setprio(1);
    #pragma unroll
    for (int mt = 0; mt < 2; mt++) {
      const int krow = kh * 32 + mt * 16 + l15;
      #pragma unroll
      for (int kc = 0; kc < 4; kc++) {
        bf16x8 kf = *(const bf16x8*)&Ksc[krow * 128 + (((kc * 4 + quad) ^ l15) * 8)];
        s[mt][0] = __builtin_amdgcn_mfma_f32_16x16x32_bf16(kf, qf[0][kc], s[mt][0], 0, 0, 0);
        s[mt][1] = __builtin_amdgcn_mfma_f32_16x16x32_bf16(kf, qf[1][kc], s[mt][1], 0, 0, 0);
      }
    }
    __builtin_amdgcn_s_setprio(0);

    float vmax[2];
    #pragma unroll
    for (int nt = 0; nt < 2; nt++) {
      // max3-fusable grouping: 3x v_max3 + 1x v_max
      float a = fmaxf(fmaxf(s[0][nt][0], s[0][nt][1]), s[0][nt][2]);
      a = fmaxf(fmaxf(a, s[0][nt][3]), s[1][nt][0]);
      a = fmaxf(fmaxf(a, s[1][nt][1]), s[1][nt][2]);
      a = fmaxf(a, s[1][nt][3]);
      a = fmaxf(a, __shfl_xor(a, 16));
      vmax[nt] = fmaxf(a, __shfl_xor(a, 32));
    }
    // T13 defer-max in exp2 domain: skip rescale while growth <= 8*log2e
    // (P <= 2^11.54 = e^8, safe in f32 accum).
    if (!__all((vmax[0] - m_i[0] <= 11.5415603f) && (vmax[1] - m_i[1] <= 11.5415603f))) {
      float alpha[2];
      #pragma unroll
      for (int nt = 0; nt < 2; nt++) {
        float mnew = fmaxf(m_i[nt], vmax[nt]);
        alpha[nt] = exp2f(m_i[nt] - mnew);
        m_i[nt] = mnew;
        l_i[nt] *= alpha[nt];
      }
      float ar[2][4];
      #pragma unroll
      for (int qt = 0; qt < 2; qt++)
        #pragma unroll
        for (int r = 0; r < 4; r++)
          ar[qt][r] = __shfl(alpha[qt], quad * 4 + r);
      #pragma unroll
      for (int qt = 0; qt < 2; qt++)
        #pragma unroll
        for (int ntd = 0; ntd < 8; ntd++)
          #pragma unroll
          for (int r = 0; r < 4; r++)
            oacc[qt][ntd][r] *= ar[qt][r];
    }
    float rs[2] = {0.f, 0.f};
    #pragma unroll
    for (int mt = 0; mt < 2; mt++)
      #pragma unroll
      for (int nt = 0; nt < 2; nt++)
        #pragma unroll
        for (int r = 0; r < 4; r++) {
          float p = exp2f(s[mt][nt][r] - m_i[nt]);
          s[mt][nt][r] = p;
          rs[nt] += p;
        }
    #pragma unroll
    for (int nt = 0; nt < 2; nt++) {
      rs[nt] += __shfl_xor(rs[nt], 16);
      rs[nt] += __shfl_xor(rs[nt], 32);
      l_i[nt] += rs[nt];
    }
    bf16x4 pk[2][2];
    #pragma unroll
    for (int mt = 0; mt < 2; mt++)
      #pragma unroll
      for (int qt = 0; qt < 2; qt++) {
        union { unsigned int u2[2]; bf16x4 v4; } pku;
        asm("v_cvt_pk_bf16_f32 %0, %1, %2"
            : "=v"(pku.u2[0]) : "v"(s[mt][qt][0]), "v"(s[mt][qt][1]));
        asm("v_cvt_pk_bf16_f32 %0, %1, %2"
            : "=v"(pku.u2[1]) : "v"(s[mt][qt][2]), "v"(s[mt][qt][3]));
        pk[mt][qt] = pku.v4;
      }

    // B2: V(t) resident for all waves; K(t+64) prefetch stays in flight.
    if (more) asm volatile("s_waitcnt vmcnt(4)" ::: "memory");
    else      asm volatile("s_waitcnt vmcnt(0)" ::: "memory");
    __builtin_amdgcn_s_barrier();

    __builtin_amdgcn_s_setprio(1);
    #pragma unroll
    for (int ntd = 0; ntd < 8; ntd++) {
      const int vrow = ntd * 16 + l15;
      #pragma unroll
      for (int mt = 0; mt < 2; mt++) {
        int phys = (kh * 4 + mt * 2 + (quad >> 1)) ^ (l15 & 7);
        bf16x4 vf = *(const bf16x4*)&Vsc[vrow * 64 + phys * 8 + (quad & 1) * 4];
        oacc[0][ntd] = __builtin_amdgcn_mfma_f32_16x16x16bf16_1k(pk[mt][0], vf, oacc[0][ntd], 0, 0, 0);
        oacc[1][ntd] = __builtin_amdgcn_mfma_f32_16x16x16bf16_1k(pk[mt][1], vf, oacc[1][ntd], 0, 0, 0);
      }
    }
    __builtin_amdgcn_s_setprio(0);

    if (more) {
      __builtin_amdgcn_s_barrier();   // B3: all PV reads of Vs done
      stageV(t + 64);                 // prefetch next V tile (drains at next B2)
    }
  }

  __syncthreads();
  if (kh == 1) {
    #pragma unroll
    for (int qt = 0; qt < 2; qt++)
      #pragma unroll
      for (int ntd = 0; ntd < 8; ntd++)
        #pragma unroll
        for (int r = 0; r < 4; r++)
          Obuf[(size_t)(qg * 32 + qt * 16 + quad * 4 + r) * 128 + ntd * 16 + l15] = oacc[qt][ntd][r];
    if (quad == 0)
      #pragma unroll
      for (int qt = 0; qt < 2; qt++)
        mlb[qg * 32 + qt * 16 + l15] = make_float2(m_i[qt], l_i[qt]);
  }
  __syncthreads();
  if (kh == 0 && quad == 0) {
    #pragma unroll
    for (int qt = 0; qt < 2; qt++) {
      float2 m1 = mlb[qg * 32 + qt * 16 + l15];
      float M  = fmaxf(m_i[qt], m1.x);
      float a0 = exp2f(m_i[qt] - M);
      float a1 = exp2f(m1.x - M);
      float Ls = l_i[qt] * a0 + m1.y * a1;
      sAr[qg * 32 + qt * 16 + l15] = make_float4(a0, a1, 1.f / Ls, 0.f);
    }
  }
  __syncthreads();
  if (kh == 0) {
    #pragma unroll
    for (int qt = 0; qt < 2; qt++)
      #pragma unroll
      for (int r = 0; r < 4; r++) {
        float4 A = sAr[qg * 32 + qt * 16 + quad * 4 + r];
        #pragma unroll
        for (int ntd = 0; ntd < 8; ntd++) {
          float o1 = Obuf[(size_t)(qg * 32 + qt * 16 + quad * 4 + r) * 128 + ntd * 16 + l15];
          float v  = (oacc[qt][ntd][r] * A.x + o1 * A.y) * A.z;
          Out[(size_t)(q0 + qt * 16 + quad * 4 + r) * DIM_ + h * D_ + ntd * 16 + l15] = f2bf(v);
        }
      }
  }
}

// ---------------------------------------------------------------- launcher
extern "C" void kernel_launch(void* const* d_in, const int* in_sizes, int n_in,
                              void* d_out, int out_size, void* d_ws, size_t ws_size,
                              hipStream_t stream) {
  const float* x       = (const float*)d_in[0];
  const float* pe      = (const float*)d_in[1];
  const float* w_qkv   = (const float*)d_in[2];
  const float* q_scale = (const float*)d_in[3];
  const float* k_scale = (const float*)d_in[4];
  const float* w_proj  = (const float*)d_in[5];
  const float* b_proj  = (const float*)d_in[6];

  unsigned short* w_qkvT  = (unsigned short*)d_ws;           // [9216][3072]
  unsigned short* w_projT = w_qkvT + 28311552;               // [3072][3072]
  unsigned short* x_b     = w_projT + 9437184;               // [2048][3072]
  unsigned short* q_r     = x_b + 6291456;                   // [H][L][D]
  unsigned short* k_r     = q_r + 6291456;
  unsigned short* vt_r    = k_r + 6291456;                   // [H][D][L]
  unsigned short* attn_b  = vt_r + 6291456;                  // [L][DIM]

  castAll<<<dim3(24, 288), 256, 0, stream>>>(
      x, x_b, w_qkv, w_qkvT, w_proj, w_projT);

  gemm_qkv<<<1152, 256, 0, stream>>>(
      x_b, w_qkvT, pe, q_scale, k_scale, q_r, k_r, vt_r);

  flash_attn<<<768, 256, 0, stream>>>(q_r, k_r, vt_r, attn_b);

  gemm_proj<<<384, 256, 0, stream>>>(
      attn_b, w_projT, b_proj, (float*)d_out, 2048, 3072, 3072);
}